// Round 4
// baseline (522.096 us; speedup 1.0000x reference)
//
#include <hip/hip_runtime.h>
#include <hip/hip_bf16.h>

typedef unsigned short bfu;
typedef __attribute__((ext_vector_type(8))) short short8;
typedef __attribute__((ext_vector_type(4))) float f32x4;

__device__ __forceinline__ bfu f2bf(float f) {
  return __builtin_bit_cast(bfu, __float2bfloat16(f));
}

__device__ __forceinline__ void gld16(const void* g, void* l) {
  __builtin_amdgcn_global_load_lds(
      (const __attribute__((address_space(1))) void*)g,
      (__attribute__((address_space(3))) void*)l, 16, 0, 0);
}

// XOR swizzle for [rows][32]-bf16 LDS tiles (64B rows), over 128B 2-row units:
// logical (row, slot16) -> physical byte offset. Involution; spreads 16
// consecutive rows' same-slot reads across all 8 bank groups (2 lanes/bank).
__device__ __forceinline__ int swz(int row, int slot) {
  const int unit = row >> 1;
  const int s8 = ((row & 1) << 2) | slot;
  return (unit << 7) + (((s8 ^ unit) & 7) << 4) + ((s8 >> 3) << 7);
}
// inverse mapping for staging: physical byte p -> (row, col-element)
__device__ __forceinline__ void unswz(int p, int& row, int& colel) {
  const int unit = p >> 7;
  const int s8 = ((p >> 4) & 7) ^ (unit & 7);
  row = (unit << 1) | (s8 >> 2);
  colel = (s8 & 3) << 3;
}

// ---------------- weight transpose + bf16 cast: WT[n][k] = W[k][n] ----------
__global__ void transpose_w(const float* __restrict__ W, bfu* __restrict__ WT,
                            int K, int N) {
  int idx = blockIdx.x * 256 + threadIdx.x;
  if (idx >= K * N) return;
  int k = idx / N, n = idx - k * N;
  WT[(size_t)n * K + k] = f2bf(W[idx]);
}

// ---------------- LayerNorm: one wave per row of 384 ------------------------
__launch_bounds__(256)
__global__ void ln_kernel(const float* __restrict__ in, const float* __restrict__ g,
                          const float* __restrict__ be, bfu* __restrict__ out) {
  const int wv = threadIdx.x >> 6, ln = threadIdx.x & 63;
  const size_t row = (size_t)blockIdx.x * 4 + wv;
  const float* p = in + row * 384;
  float v[6], s = 0.f, ss = 0.f;
#pragma unroll
  for (int i = 0; i < 6; i++) { v[i] = p[i * 64 + ln]; s += v[i]; ss += v[i] * v[i]; }
#pragma unroll
  for (int m = 1; m < 64; m <<= 1) { s += __shfl_xor(s, m); ss += __shfl_xor(ss, m); }
  const float mean = s * (1.f / 384.f);
  const float rs = rsqrtf(ss * (1.f / 384.f) - mean * mean + 1e-5f);
  bfu* q = out + row * 384;
#pragma unroll
  for (int i = 0; i < 6; i++) {
    const int c = i * 64 + ln;
    q[c] = f2bf((v[i] - mean) * rs * g[c] + be[c]);
  }
}

// ---------------- GEMM: C[M,N] = A[M,K](bf16) @ BT[N,K](bf16)^T -------------
// 128x128 tile, BK=32, 4 waves (2x2). 3-buffer ring, one raw s_barrier per
// K-step, counted vmcnt. LDS tiles XOR-swizzled (linear gld_lds dest, inverse-
// swizzled global source, swizzled ds_read).
template <int BIAS, int RELU, int OUTBF>
__launch_bounds__(256)
__global__ void gemm_kernel(const bfu* __restrict__ A, const bfu* __restrict__ Bt,
                            const float* __restrict__ bias,
                            void* __restrict__ Cout, int N, int K, int ntn) {
  __shared__ bfu a_sm[3][128 * 32];
  __shared__ bfu b_sm[3][128 * 32];
  const int tid = threadIdx.x;
  const int wv = tid >> 6, ln = tid & 63;
  const int cpx = gridDim.x >> 3;
  const int wg = (blockIdx.x & 7) * cpx + (blockIdx.x >> 3);
  const int bm = wg / ntn, bn = wg - bm * ntn;
  const int m0 = bm << 7, n0 = bn << 7;
  const int wr = wv >> 1, wc = wv & 1;
  const int fr = ln & 15, fslot = ln >> 4;

  f32x4 acc[4][4];
#pragma unroll
  for (int i = 0; i < 4; i++)
#pragma unroll
    for (int j = 0; j < 4; j++) acc[i][j] = f32x4{0.f, 0.f, 0.f, 0.f};

  auto stage = [&](int buf, int kt) {
#pragma unroll
    for (int i = 0; i < 2; ++i) {
      const int c = wv * 2 + i;                    // chunk 0..7 (1 KB each)
      const int p = c * 1024 + (ln << 4);          // this lane's linear dest
      int r, colel;
      unswz(p, r, colel);
      const int col = kt * 32 + colel;
      gld16(A  + (size_t)(m0 + r) * K + col, (char*)a_sm[buf] + c * 1024);
      gld16(Bt + (size_t)(n0 + r) * K + col, (char*)b_sm[buf] + c * 1024);
    }
  };

  const int nk = K >> 5;
  stage(0, 0);
  if (nk > 1) stage(1, 1);

  int cb = 0;
  for (int kt = 0; kt < nk; ++kt) {
    if (kt + 1 < nk) asm volatile("s_waitcnt vmcnt(4)" ::: "memory");
    else             asm volatile("s_waitcnt vmcnt(0)" ::: "memory");
    __builtin_amdgcn_s_barrier();
    __builtin_amdgcn_sched_barrier(0);
    if (kt + 2 < nk) {
      int sb = cb + 2; if (sb >= 3) sb -= 3;
      stage(sb, kt + 2);
    }
    short8 af[4], bfr[4];
#pragma unroll
    for (int mi = 0; mi < 4; mi++)
      af[mi] = *(const short8*)((const char*)a_sm[cb] + swz(wr * 64 + mi * 16 + fr, fslot));
#pragma unroll
    for (int ni = 0; ni < 4; ni++)
      bfr[ni] = *(const short8*)((const char*)b_sm[cb] + swz(wc * 64 + ni * 16 + fr, fslot));
#pragma unroll
    for (int mi = 0; mi < 4; mi++)
#pragma unroll
      for (int ni = 0; ni < 4; ni++)
        acc[mi][ni] = __builtin_amdgcn_mfma_f32_16x16x32_bf16(af[mi], bfr[ni], acc[mi][ni], 0, 0, 0);
    cb = (cb + 1 == 3) ? 0 : cb + 1;
  }

#pragma unroll
  for (int mi = 0; mi < 4; mi++) {
#pragma unroll
    for (int ni = 0; ni < 4; ni++) {
      const int row = m0 + wr * 64 + mi * 16 + ((ln >> 4) << 2);
      const int col = n0 + wc * 64 + ni * 16 + fr;
      float bv = 0.f;
      if (BIAS) bv = bias[col];
#pragma unroll
      for (int r = 0; r < 4; r++) {
        float v = acc[mi][ni][r] + bv;
        if (RELU) v = fmaxf(v, 0.f);
        const size_t idx = (size_t)(row + r) * N + col;
        if (OUTBF) ((bfu*)Cout)[idx] = f2bf(v);
        else       ((float*)Cout)[idx] = v;
      }
    }
  }
}

// ---------------- full-row GEMM: C[M,384] = A[M,K] @ Bt[384,K]^T ------------
// BM=128, BN=384, 8 waves (2x4, 64x96 each), BK=32. 4-buffer ring, one raw
// s_barrier + counted vmcnt per K-step, swizzled LDS. Epilogue: +bias
// +residual, then LN (LN=1, bf16 out) or plain fp32 out (LN=0).
template <int LN>
__launch_bounds__(512)
__global__ void row_gemm(const bfu* __restrict__ A, const bfu* __restrict__ Bt,
                         const float* __restrict__ bias, const float* __restrict__ res,
                         const float* __restrict__ g, const float* __restrict__ be,
                         void* __restrict__ Cout, int K) {
  __shared__ bfu a_sm[4][128 * 32];
  __shared__ bfu b_sm[4][384 * 32];
  __shared__ float lnp[4][128][2];
  const int tid = threadIdx.x;
  const int wv = tid >> 6, ln = tid & 63;
  const int wr = wv >> 2, wc = wv & 3;          // 2 x 4 wave grid
  const int fr = ln & 15, fslot = ln >> 4;
  const int m0 = blockIdx.x << 7;

  f32x4 acc[4][6];
#pragma unroll
  for (int i = 0; i < 4; i++)
#pragma unroll
    for (int j = 0; j < 6; j++) acc[i][j] = f32x4{0.f, 0.f, 0.f, 0.f};

  auto stage = [&](int buf, int kt) {
#pragma unroll
    for (int i = 0; i < 4; ++i) {
      const int c = wv * 4 + i;                  // 32 chunks: 8 A + 24 B
      const int cc = (c < 8) ? c : (c - 8);
      const int p = cc * 1024 + (ln << 4);
      int r, colel;
      unswz(p, r, colel);
      const int col = kt * 32 + colel;
      if (c < 8)
        gld16(A + (size_t)(m0 + r) * K + col, (char*)a_sm[buf] + cc * 1024);
      else
        gld16(Bt + (size_t)r * K + col, (char*)b_sm[buf] + cc * 1024);
    }
  };

  const int nk = K >> 5;
#pragma unroll
  for (int i = 0; i < 3; ++i)
    if (i < nk) stage(i, i);

  for (int kt = 0; kt < nk; ++kt) {
    const int rem = nk - 1 - kt;   // tiles staged beyond kt
    if (rem >= 2)      asm volatile("s_waitcnt vmcnt(8)" ::: "memory");
    else if (rem == 1) asm volatile("s_waitcnt vmcnt(4)" ::: "memory");
    else               asm volatile("s_waitcnt vmcnt(0)" ::: "memory");
    __builtin_amdgcn_s_barrier();
    __builtin_amdgcn_sched_barrier(0);
    if (kt + 3 < nk) stage((kt + 3) & 3, kt + 3);
    const int cb = kt & 3;
    short8 af[4], bfr[6];
#pragma unroll
    for (int mi = 0; mi < 4; mi++)
      af[mi] = *(const short8*)((const char*)a_sm[cb] + swz(wr * 64 + mi * 16 + fr, fslot));
#pragma unroll
    for (int ni = 0; ni < 6; ni++)
      bfr[ni] = *(const short8*)((const char*)b_sm[cb] + swz(wc * 96 + ni * 16 + fr, fslot));
#pragma unroll
    for (int mi = 0; mi < 4; mi++)
#pragma unroll
      for (int ni = 0; ni < 6; ni++)
        acc[mi][ni] = __builtin_amdgcn_mfma_f32_16x16x32_bf16(af[mi], bfr[ni], acc[mi][ni], 0, 0, 0);
  }

  const int rq = (ln >> 4) << 2;
#pragma unroll
  for (int mi = 0; mi < 4; mi++) {
    const int row = wr * 64 + mi * 16 + rq;
#pragma unroll
    for (int ni = 0; ni < 6; ni++) {
      const int col = wc * 96 + ni * 16 + fr;
      const float bv = bias[col];
#pragma unroll
      for (int r = 0; r < 4; r++)
        acc[mi][ni][r] += bv + res[(size_t)(m0 + row + r) * 384 + col];
    }
  }

  if (LN) {
#pragma unroll
    for (int mi = 0; mi < 4; mi++) {
      float s[4] = {0.f, 0.f, 0.f, 0.f}, ss[4] = {0.f, 0.f, 0.f, 0.f};
#pragma unroll
      for (int ni = 0; ni < 6; ni++)
#pragma unroll
        for (int r = 0; r < 4; r++) {
          const float v = acc[mi][ni][r];
          s[r] += v; ss[r] += v * v;
        }
#pragma unroll
      for (int m = 1; m < 16; m <<= 1)
#pragma unroll
        for (int r = 0; r < 4; r++) {
          s[r] += __shfl_xor(s[r], m);
          ss[r] += __shfl_xor(ss[r], m);
        }
      if (fr == 0) {
#pragma unroll
        for (int r = 0; r < 4; r++) {
          lnp[wc][wr * 64 + mi * 16 + rq + r][0] = s[r];
          lnp[wc][wr * 64 + mi * 16 + rq + r][1] = ss[r];
        }
      }
    }
    __syncthreads();
#pragma unroll
    for (int mi = 0; mi < 4; mi++) {
#pragma unroll
      for (int r = 0; r < 4; r++) {
        const int row = wr * 64 + mi * 16 + rq + r;
        const float sm = lnp[0][row][0] + lnp[1][row][0] + lnp[2][row][0] + lnp[3][row][0];
        const float sq = lnp[0][row][1] + lnp[1][row][1] + lnp[2][row][1] + lnp[3][row][1];
        const float mean = sm * (1.f / 384.f);
        const float rs = rsqrtf(sq * (1.f / 384.f) - mean * mean + 1e-5f);
#pragma unroll
        for (int ni = 0; ni < 6; ni++) {
          const int col = wc * 96 + ni * 16 + fr;
          ((bfu*)Cout)[(size_t)(m0 + row) * 384 + col] =
              f2bf((acc[mi][ni][r] - mean) * rs * g[col] + be[col]);
        }
      }
    }
  } else {
#pragma unroll
    for (int mi = 0; mi < 4; mi++) {
      const int row = wr * 64 + mi * 16 + rq;
#pragma unroll
      for (int ni = 0; ni < 6; ni++) {
        const int col = wc * 96 + ni * 16 + fr;
#pragma unroll
        for (int r = 0; r < 4; r++)
          ((float*)Cout)[(size_t)(m0 + row + r) * 384 + col] = acc[mi][ni][r];
      }
    }
  }
}

// ---------------- fused causal attention: 1 block per (b,h), 8 waves --------
#define KPAD 72
#define VPAD 264
#define PPAD 264

__launch_bounds__(512)
__global__ void attn_kernel(const bfu* __restrict__ qkv, bfu* __restrict__ ob) {
  __shared__ bfu k_sm[256 * KPAD];
  __shared__ bfu vt_sm[64 * VPAD];
  __shared__ bfu p_sm[8 * 16 * PPAD];
  const int b = blockIdx.x / 6, h = blockIdx.x - b * 6;
  const int tid = threadIdx.x;
  const int wv = tid >> 6, ln = tid & 63;
  const int fr = ln & 15, fc = (ln >> 4) << 3;
  const size_t inbase = (size_t)b * 256 * 1152 + h * 64;  // qkv row stride 1152
  const bfu* qb = qkv + inbase;
  const bfu* kb = qkv + inbase + 384;
  const bfu* vb = qkv + inbase + 768;
  const size_t obase = (size_t)b * 256 * 384 + h * 64;

  {  // stage K row-major (padded) and V transposed (padded)
    const int row = tid >> 1;
    const int dh = (tid & 1) << 5;
    const bfu* kg = kb + (size_t)row * 1152 + dh;
    const bfu* vg = vb + (size_t)row * 1152 + dh;
#pragma unroll
    for (int i = 0; i < 4; i++) {
      short8 t8 = *(const short8*)(kg + i * 8);
      *(short8*)&k_sm[row * KPAD + dh + i * 8] = t8;
      short8 v8 = *(const short8*)(vg + i * 8);
#pragma unroll
      for (int j = 0; j < 8; j++)
        vt_sm[(dh + i * 8 + j) * VPAD + row] = (bfu)v8[j];
    }
  }
  __syncthreads();

  bfu* pw = &p_sm[wv * 16 * PPAD];
  const int rq = (ln >> 4) << 2;

#pragma unroll
  for (int si = 0; si < 2; ++si) {
    const int s = si ? (15 - wv) : wv;    // balanced causal work: {w, 15-w}
    const int qr0 = s << 4;
    const int nf = s + 1;                 // kv fragments needed (causal)
    short8 aq[2];
#pragma unroll
    for (int dc = 0; dc < 2; dc++)
      aq[dc] = *(const short8*)(qb + (size_t)(qr0 + fr) * 1152 + dc * 32 + fc);

    f32x4 sacc[16];
#pragma unroll
    for (int f = 0; f < 16; f++) sacc[f] = f32x4{0.f, 0.f, 0.f, 0.f};
#pragma unroll
    for (int f = 0; f < 16; f++) if (f < nf) {
#pragma unroll
      for (int dc = 0; dc < 2; dc++) {
        short8 kf = *(const short8*)&k_sm[(f * 16 + fr) * KPAD + dc * 32 + fc];
        sacc[f] = __builtin_amdgcn_mfma_f32_16x16x32_bf16(aq[dc], kf, sacc[f], 0, 0, 0);
      }
    }
    float mr[4] = {-3e38f, -3e38f, -3e38f, -3e38f};
#pragma unroll
    for (int f = 0; f < 16; f++) if (f < nf) {
#pragma unroll
      for (int r = 0; r < 4; r++) {
        float sv = sacc[f][r] * 0.125f;
        if (f * 16 + fr > qr0 + rq + r) sv = -3e38f;
        sacc[f][r] = sv;
        mr[r] = fmaxf(mr[r], sv);
      }
    }
#pragma unroll
    for (int msk = 1; msk < 16; msk <<= 1) {
#pragma unroll
      for (int r = 0; r < 4; r++) mr[r] = fmaxf(mr[r], __shfl_xor(mr[r], msk));
    }
    float ls[4] = {0.f, 0.f, 0.f, 0.f};
#pragma unroll
    for (int f = 0; f < 16; f++) if (f < nf) {
#pragma unroll
      for (int r = 0; r < 4; r++) {
        float p = __expf(sacc[f][r] - mr[r]);
        sacc[f][r] = p;
        ls[r] += p;
      }
    }
#pragma unroll
    for (int msk = 1; msk < 16; msk <<= 1) {
#pragma unroll
      for (int r = 0; r < 4; r++) ls[r] += __shfl_xor(ls[r], msk);
    }
#pragma unroll
    for (int f = 0; f < 16; f++) if (f < nf) {
#pragma unroll
      for (int r = 0; r < 4; r++)
        pw[(rq + r) * PPAD + f * 16 + fr] = f2bf(sacc[f][r]);
    }
    if (nf & 1) {
#pragma unroll
      for (int r = 0; r < 4; r++) pw[(rq + r) * PPAD + nf * 16 + fr] = 0;
    }
    f32x4 oc[4];
#pragma unroll
    for (int n = 0; n < 4; n++) oc[n] = f32x4{0.f, 0.f, 0.f, 0.f};
    const int kcs = (nf + 1) >> 1;
#pragma unroll
    for (int kc = 0; kc < 8; ++kc) if (kc < kcs) {
      short8 pa = *(const short8*)&pw[fr * PPAD + kc * 32 + fc];
#pragma unroll
      for (int n = 0; n < 4; n++) {
        short8 vf = *(const short8*)&vt_sm[(n * 16 + fr) * VPAD + kc * 32 + fc];
        oc[n] = __builtin_amdgcn_mfma_f32_16x16x32_bf16(pa, vf, oc[n], 0, 0, 0);
      }
    }
    float inv[4];
#pragma unroll
    for (int r = 0; r < 4; r++) inv[r] = 1.f / ls[r];
#pragma unroll
    for (int n = 0; n < 4; n++) {
#pragma unroll
      for (int r = 0; r < 4; r++)
        ob[obase + (size_t)(qr0 + rq + r) * 384 + n * 16 + fr] = f2bf(oc[n][r] * inv[r]);
    }
  }
}

// ---------------- orchestration ---------------------------------------------
extern "C" void kernel_launch(void* const* d_in, const int* in_sizes, int n_in,
                              void* d_out, int out_size, void* d_ws, size_t ws_size,
                              hipStream_t stream) {
  const float* x   = (const float*)d_in[0];
  const float* Wq  = (const float*)d_in[1];
  const float* Wk  = (const float*)d_in[2];
  const float* Wv  = (const float*)d_in[3];
  const float* Wo  = (const float*)d_in[4];
  const float* bo  = (const float*)d_in[5];
  const float* W1  = (const float*)d_in[6];
  const float* b1  = (const float*)d_in[7];
  const float* W2  = (const float*)d_in[8];
  const float* b2  = (const float*)d_in[9];
  const float* g1  = (const float*)d_in[10];
  const float* be1 = (const float*)d_in[11];
  const float* g2  = (const float*)d_in[12];
  const float* be2 = (const float*)d_in[13];
  float* out = (float*)d_out;
  char* ws = (char*)d_ws;

  // workspace layout (255.2 MB total; phases strictly ordered on the stream)
  bfu* wqkvT = (bfu*)(ws + 0);          // 1152x384 bf16 = 884736 B
  bfu* woT   = (bfu*)(ws + 884736);     // 294912
  bfu* w1T   = (bfu*)(ws + 1179648);    // 1179648
  bfu* w2T   = (bfu*)(ws + 2359296);    // 1179648
  char* H    = ws + 3538944;            // 50.3 MB: h2
  char* BIG  = H + 50331648;            // 201.3 MB: {h | attn} + qkv -> ab
  bfu* hb    = (bfu*)BIG;               // 50.3 MB (dead after QKV gemm)
  bfu* qkvb  = (bfu*)(BIG + 50331648);  // 151 MB (dead after attention)
  bfu* attnb = (bfu*)BIG;               // reuses hb region
  bfu* h2b   = (bfu*)H;
  bfu* ab    = (bfu*)BIG;               // 201.3 MB (clobbers attnb+qkvb, both dead)

  // 1) weights -> bf16 transposed (Wq/Wk/Wv packed into one [1152][384])
  transpose_w<<<576, 256, 0, stream>>>(Wq, wqkvT, 384, 384);
  transpose_w<<<576, 256, 0, stream>>>(Wk, wqkvT + 384 * 384, 384, 384);
  transpose_w<<<576, 256, 0, stream>>>(Wv, wqkvT + 2 * 384 * 384, 384, 384);
  transpose_w<<<576, 256, 0, stream>>>(Wo, woT, 384, 384);
  transpose_w<<<2304, 256, 0, stream>>>(W1, w1T, 384, 1536);
  transpose_w<<<2304, 256, 0, stream>>>(W2, w2T, 1536, 384);

  // 2) LN1
  ln_kernel<<<16384, 256, 0, stream>>>(x, g1, be1, hb);

  // 3) fused QKV GEMM (N=1152, bf16 out)
  gemm_kernel<0, 0, 1><<<4608, 256, 0, stream>>>(hb, wqkvT, nullptr, qkvb, 1152, 384, 9);

  // 4) fused causal attention (reads packed qkv, stride 1152)
  attn_kernel<<<1536, 512, 0, stream>>>(qkvb, attnb);

  // 5) proj + bias + residual(x) + LN2 fused -> h2 (bf16)
  row_gemm<1><<<512, 512, 0, stream>>>(attnb, woT, bo, x, g2, be2, h2b, 384);

  // 6) FFN1 (+bias+ReLU, bf16 out)
  gemm_kernel<1, 1, 1><<<6144, 256, 0, stream>>>(h2b, w1T, b1, ab, 1536, 384, 12);

  // 7) FFN2 + bias + residual(x) -> out (fp32)
  row_gemm<0><<<512, 512, 0, stream>>>(ab, w2T, b2, x, nullptr, nullptr, out, 1536);
}

// Round 5
// 519.673 us; speedup vs baseline: 1.0047x; 1.0047x over previous
//
#include <hip/hip_runtime.h>
#include <hip/hip_bf16.h>

typedef unsigned short bfu;
typedef __attribute__((ext_vector_type(8))) short short8;
typedef __attribute__((ext_vector_type(4))) float f32x4;

__device__ __forceinline__ bfu f2bf(float f) {
  return __builtin_bit_cast(bfu, __float2bfloat16(f));
}

__device__ __forceinline__ void gld16(const void* g, void* l) {
  __builtin_amdgcn_global_load_lds(
      (const __attribute__((address_space(1))) void*)g,
      (__attribute__((address_space(3))) void*)l, 16, 0, 0);
}

// XOR swizzle for [rows][32]-bf16 LDS tiles (64B rows), over 128B 2-row units:
// logical (row, slot16) -> physical byte offset. Involution; spreads 16
// consecutive rows' same-slot reads across all 8 bank groups (2 lanes/bank).
__device__ __forceinline__ int swz(int row, int slot) {
  const int unit = row >> 1;
  const int s8 = ((row & 1) << 2) | slot;
  return (unit << 7) + (((s8 ^ unit) & 7) << 4) + ((s8 >> 3) << 7);
}
// inverse mapping for staging: physical byte p -> (row, col-element)
__device__ __forceinline__ void unswz(int p, int& row, int& colel) {
  const int unit = p >> 7;
  const int s8 = ((p >> 4) & 7) ^ (unit & 7);
  row = (unit << 1) | (s8 >> 2);
  colel = (s8 & 3) << 3;
}

// ---------------- weight transpose + bf16 cast: WT[n][k] = W[k][n] ----------
__global__ void transpose_w(const float* __restrict__ W, bfu* __restrict__ WT,
                            int K, int N) {
  int idx = blockIdx.x * 256 + threadIdx.x;
  if (idx >= K * N) return;
  int k = idx / N, n = idx - k * N;
  WT[(size_t)n * K + k] = f2bf(W[idx]);
}

// ---------------- LayerNorm: one wave per row of 384 ------------------------
__launch_bounds__(256)
__global__ void ln_kernel(const float* __restrict__ in, const float* __restrict__ g,
                          const float* __restrict__ be, bfu* __restrict__ out) {
  const int wv = threadIdx.x >> 6, ln = threadIdx.x & 63;
  const size_t row = (size_t)blockIdx.x * 4 + wv;
  const float* p = in + row * 384;
  float v[6], s = 0.f, ss = 0.f;
#pragma unroll
  for (int i = 0; i < 6; i++) { v[i] = p[i * 64 + ln]; s += v[i]; ss += v[i] * v[i]; }
#pragma unroll
  for (int m = 1; m < 64; m <<= 1) { s += __shfl_xor(s, m); ss += __shfl_xor(ss, m); }
  const float mean = s * (1.f / 384.f);
  const float rs = rsqrtf(ss * (1.f / 384.f) - mean * mean + 1e-5f);
  bfu* q = out + row * 384;
#pragma unroll
  for (int i = 0; i < 6; i++) {
    const int c = i * 64 + ln;
    q[c] = f2bf((v[i] - mean) * rs * g[c] + be[c]);
  }
}

// ---------------- GEMM: C[M,N] = A[M,K](bf16) @ BT[N,K](bf16)^T -------------
// 256x128 tile, BK=32, 4 waves (2x2), wave = 128x64 (42.7 FLOP per LDS byte).
// 3-buffer ring, one raw s_barrier per K-step, counted vmcnt, swizzled LDS.
template <int BIAS, int RELU, int OUTBF>
__launch_bounds__(256, 2)
__global__ void gemm_kernel(const bfu* __restrict__ A, const bfu* __restrict__ Bt,
                            const float* __restrict__ bias,
                            void* __restrict__ Cout, int N, int K, int ntn) {
  __shared__ bfu a_sm[3][256 * 32];
  __shared__ bfu b_sm[3][128 * 32];
  const int tid = threadIdx.x;
  const int wv = tid >> 6, ln = tid & 63;
  const int cpx = gridDim.x >> 3;
  const int wg = (blockIdx.x & 7) * cpx + (blockIdx.x >> 3);
  const int bm = wg / ntn, bn = wg - bm * ntn;
  const int m0 = bm << 8, n0 = bn << 7;
  const int wr = wv >> 1, wc = wv & 1;    // wave = rows [wr*128,+128), cols [wc*64,+64)
  const int fr = ln & 15, fslot = ln >> 4;

  f32x4 acc[8][4];
#pragma unroll
  for (int i = 0; i < 8; i++)
#pragma unroll
    for (int j = 0; j < 4; j++) acc[i][j] = f32x4{0.f, 0.f, 0.f, 0.f};

  auto stage = [&](int buf, int kt) {   // 6 loads per wave: 4 A-chunks + 2 B-chunks
#pragma unroll
    for (int i = 0; i < 6; ++i) {
      if (i < 4) {
        const int c = wv * 4 + i;                  // A chunks 0..15 (1 KB each)
        const int p = c * 1024 + (ln << 4);
        int r, colel; unswz(p, r, colel);
        gld16(A + (size_t)(m0 + r) * K + kt * 32 + colel, (char*)a_sm[buf] + c * 1024);
      } else {
        const int c = wv * 2 + (i - 4);            // B chunks 0..7
        const int p = c * 1024 + (ln << 4);
        int r, colel; unswz(p, r, colel);
        gld16(Bt + (size_t)(n0 + r) * K + kt * 32 + colel, (char*)b_sm[buf] + c * 1024);
      }
    }
  };

  const int nk = K >> 5;
  stage(0, 0);
  stage(1, 1);

  int cb = 0;
  for (int kt = 0; kt < nk; ++kt) {
    // drain tile kt's own 6 loads; leave tile kt+1's 6 in flight
    if (kt + 1 < nk) asm volatile("s_waitcnt vmcnt(6)" ::: "memory");
    else             asm volatile("s_waitcnt vmcnt(0)" ::: "memory");
    __builtin_amdgcn_s_barrier();
    __builtin_amdgcn_sched_barrier(0);
    if (kt + 2 < nk) {
      int sb = cb + 2; if (sb >= 3) sb -= 3;
      stage(sb, kt + 2);
    }
    short8 af[8], bfr[4];
#pragma unroll
    for (int mi = 0; mi < 8; mi++)
      af[mi] = *(const short8*)((const char*)a_sm[cb] + swz(wr * 128 + mi * 16 + fr, fslot));
#pragma unroll
    for (int ni = 0; ni < 4; ni++)
      bfr[ni] = *(const short8*)((const char*)b_sm[cb] + swz(wc * 64 + ni * 16 + fr, fslot));
    __builtin_amdgcn_s_setprio(1);
#pragma unroll
    for (int mi = 0; mi < 8; mi++)
#pragma unroll
      for (int ni = 0; ni < 4; ni++)
        acc[mi][ni] = __builtin_amdgcn_mfma_f32_16x16x32_bf16(af[mi], bfr[ni], acc[mi][ni], 0, 0, 0);
    __builtin_amdgcn_s_setprio(0);
    cb = (cb + 1 == 3) ? 0 : cb + 1;
  }

#pragma unroll
  for (int mi = 0; mi < 8; mi++) {
#pragma unroll
    for (int ni = 0; ni < 4; ni++) {
      const int row = m0 + wr * 128 + mi * 16 + ((ln >> 4) << 2);
      const int col = n0 + wc * 64 + ni * 16 + fr;
      float bv = 0.f;
      if (BIAS) bv = bias[col];
#pragma unroll
      for (int r = 0; r < 4; r++) {
        float v = acc[mi][ni][r] + bv;
        if (RELU) v = fmaxf(v, 0.f);
        const size_t idx = (size_t)(row + r) * N + col;
        if (OUTBF) ((bfu*)Cout)[idx] = f2bf(v);
        else       ((float*)Cout)[idx] = v;
      }
    }
  }
}

// ---------------- full-row GEMM: C[M,384] = A[M,K] @ Bt[384,K]^T ------------
// BM=128, BN=384, 8 waves (2x4, 64x96 each), BK=32. 4-buffer ring, one raw
// s_barrier + counted vmcnt per K-step, swizzled LDS. Epilogue: +bias
// +residual, then LN (LN=1, bf16 out) or plain fp32 out (LN=0).
template <int LN>
__launch_bounds__(512)
__global__ void row_gemm(const bfu* __restrict__ A, const bfu* __restrict__ Bt,
                         const float* __restrict__ bias, const float* __restrict__ res,
                         const float* __restrict__ g, const float* __restrict__ be,
                         void* __restrict__ Cout, int K) {
  __shared__ bfu a_sm[4][128 * 32];
  __shared__ bfu b_sm[4][384 * 32];
  __shared__ float lnp[4][128][2];
  const int tid = threadIdx.x;
  const int wv = tid >> 6, ln = tid & 63;
  const int wr = wv >> 2, wc = wv & 3;          // 2 x 4 wave grid
  const int fr = ln & 15, fslot = ln >> 4;
  const int m0 = blockIdx.x << 7;

  f32x4 acc[4][6];
#pragma unroll
  for (int i = 0; i < 4; i++)
#pragma unroll
    for (int j = 0; j < 6; j++) acc[i][j] = f32x4{0.f, 0.f, 0.f, 0.f};

  auto stage = [&](int buf, int kt) {
#pragma unroll
    for (int i = 0; i < 4; ++i) {
      const int c = wv * 4 + i;                  // 32 chunks: 8 A + 24 B
      const int cc = (c < 8) ? c : (c - 8);
      const int p = cc * 1024 + (ln << 4);
      int r, colel;
      unswz(p, r, colel);
      const int col = kt * 32 + colel;
      if (c < 8)
        gld16(A + (size_t)(m0 + r) * K + col, (char*)a_sm[buf] + cc * 1024);
      else
        gld16(Bt + (size_t)r * K + col, (char*)b_sm[buf] + cc * 1024);
    }
  };

  const int nk = K >> 5;
#pragma unroll
  for (int i = 0; i < 3; ++i)
    if (i < nk) stage(i, i);

  for (int kt = 0; kt < nk; ++kt) {
    const int rem = nk - 1 - kt;   // tiles staged beyond kt
    if (rem >= 2)      asm volatile("s_waitcnt vmcnt(8)" ::: "memory");
    else if (rem == 1) asm volatile("s_waitcnt vmcnt(4)" ::: "memory");
    else               asm volatile("s_waitcnt vmcnt(0)" ::: "memory");
    __builtin_amdgcn_s_barrier();
    __builtin_amdgcn_sched_barrier(0);
    if (kt + 3 < nk) stage((kt + 3) & 3, kt + 3);
    const int cb = kt & 3;
    short8 af[4], bfr[6];
#pragma unroll
    for (int mi = 0; mi < 4; mi++)
      af[mi] = *(const short8*)((const char*)a_sm[cb] + swz(wr * 64 + mi * 16 + fr, fslot));
#pragma unroll
    for (int ni = 0; ni < 6; ni++)
      bfr[ni] = *(const short8*)((const char*)b_sm[cb] + swz(wc * 96 + ni * 16 + fr, fslot));
    __builtin_amdgcn_s_setprio(1);
#pragma unroll
    for (int mi = 0; mi < 4; mi++)
#pragma unroll
      for (int ni = 0; ni < 6; ni++)
        acc[mi][ni] = __builtin_amdgcn_mfma_f32_16x16x32_bf16(af[mi], bfr[ni], acc[mi][ni], 0, 0, 0);
    __builtin_amdgcn_s_setprio(0);
  }

  const int rq = (ln >> 4) << 2;
#pragma unroll
  for (int mi = 0; mi < 4; mi++) {
    const int row = wr * 64 + mi * 16 + rq;
#pragma unroll
    for (int ni = 0; ni < 6; ni++) {
      const int col = wc * 96 + ni * 16 + fr;
      const float bv = bias[col];
#pragma unroll
      for (int r = 0; r < 4; r++)
        acc[mi][ni][r] += bv + res[(size_t)(m0 + row + r) * 384 + col];
    }
  }

  if (LN) {
#pragma unroll
    for (int mi = 0; mi < 4; mi++) {
      float s[4] = {0.f, 0.f, 0.f, 0.f}, ss[4] = {0.f, 0.f, 0.f, 0.f};
#pragma unroll
      for (int ni = 0; ni < 6; ni++)
#pragma unroll
        for (int r = 0; r < 4; r++) {
          const float v = acc[mi][ni][r];
          s[r] += v; ss[r] += v * v;
        }
#pragma unroll
      for (int m = 1; m < 16; m <<= 1)
#pragma unroll
        for (int r = 0; r < 4; r++) {
          s[r] += __shfl_xor(s[r], m);
          ss[r] += __shfl_xor(ss[r], m);
        }
      if (fr == 0) {
#pragma unroll
        for (int r = 0; r < 4; r++) {
          lnp[wc][wr * 64 + mi * 16 + rq + r][0] = s[r];
          lnp[wc][wr * 64 + mi * 16 + rq + r][1] = ss[r];
        }
      }
    }
    __syncthreads();
#pragma unroll
    for (int mi = 0; mi < 4; mi++) {
#pragma unroll
      for (int r = 0; r < 4; r++) {
        const int row = wr * 64 + mi * 16 + rq + r;
        const float sm = lnp[0][row][0] + lnp[1][row][0] + lnp[2][row][0] + lnp[3][row][0];
        const float sq = lnp[0][row][1] + lnp[1][row][1] + lnp[2][row][1] + lnp[3][row][1];
        const float mean = sm * (1.f / 384.f);
        const float rs = rsqrtf(sq * (1.f / 384.f) - mean * mean + 1e-5f);
#pragma unroll
        for (int ni = 0; ni < 6; ni++) {
          const int col = wc * 96 + ni * 16 + fr;
          ((bfu*)Cout)[(size_t)(m0 + row) * 384 + col] =
              f2bf((acc[mi][ni][r] - mean) * rs * g[col] + be[col]);
        }
      }
    }
  } else {
#pragma unroll
    for (int mi = 0; mi < 4; mi++) {
      const int row = wr * 64 + mi * 16 + rq;
#pragma unroll
      for (int ni = 0; ni < 6; ni++) {
        const int col = wc * 96 + ni * 16 + fr;
#pragma unroll
        for (int r = 0; r < 4; r++)
          ((float*)Cout)[(size_t)(m0 + row + r) * 384 + col] = acc[mi][ni][r];
      }
    }
  }
}

// ---------------- fused causal attention: 1 block per (b,h), 8 waves --------
#define KPAD 72
#define VPAD 264
#define PPAD 264

__launch_bounds__(512)
__global__ void attn_kernel(const bfu* __restrict__ qkv, bfu* __restrict__ ob) {
  __shared__ bfu k_sm[256 * KPAD];
  __shared__ bfu vt_sm[64 * VPAD];
  __shared__ bfu p_sm[8 * 16 * PPAD];
  const int b = blockIdx.x / 6, h = blockIdx.x - b * 6;
  const int tid = threadIdx.x;
  const int wv = tid >> 6, ln = tid & 63;
  const int fr = ln & 15, fc = (ln >> 4) << 3;
  const size_t inbase = (size_t)b * 256 * 1152 + h * 64;  // qkv row stride 1152
  const bfu* qb = qkv + inbase;
  const bfu* kb = qkv + inbase + 384;
  const bfu* vb = qkv + inbase + 768;
  const size_t obase = (size_t)b * 256 * 384 + h * 64;

  {  // stage K row-major (padded) and V transposed (padded)
    const int row = tid >> 1;
    const int dh = (tid & 1) << 5;
    const bfu* kg = kb + (size_t)row * 1152 + dh;
    const bfu* vg = vb + (size_t)row * 1152 + dh;
#pragma unroll
    for (int i = 0; i < 4; i++) {
      short8 t8 = *(const short8*)(kg + i * 8);
      *(short8*)&k_sm[row * KPAD + dh + i * 8] = t8;
      short8 v8 = *(const short8*)(vg + i * 8);
#pragma unroll
      for (int j = 0; j < 8; j++)
        vt_sm[(dh + i * 8 + j) * VPAD + row] = (bfu)v8[j];
    }
  }
  __syncthreads();

  bfu* pw = &p_sm[wv * 16 * PPAD];
  const int rq = (ln >> 4) << 2;

#pragma unroll
  for (int si = 0; si < 2; ++si) {
    const int s = si ? (15 - wv) : wv;    // balanced causal work: {w, 15-w}
    const int qr0 = s << 4;
    const int nf = s + 1;                 // kv fragments needed (causal)
    short8 aq[2];
#pragma unroll
    for (int dc = 0; dc < 2; dc++)
      aq[dc] = *(const short8*)(qb + (size_t)(qr0 + fr) * 1152 + dc * 32 + fc);

    f32x4 sacc[16];
#pragma unroll
    for (int f = 0; f < 16; f++) sacc[f] = f32x4{0.f, 0.f, 0.f, 0.f};
#pragma unroll
    for (int f = 0; f < 16; f++) if (f < nf) {
#pragma unroll
      for (int dc = 0; dc < 2; dc++) {
        short8 kf = *(const short8*)&k_sm[(f * 16 + fr) * KPAD + dc * 32 + fc];
        sacc[f] = __builtin_amdgcn_mfma_f32_16x16x32_bf16(aq[dc], kf, sacc[f], 0, 0, 0);
      }
    }
    float mr[4] = {-3e38f, -3e38f, -3e38f, -3e38f};
#pragma unroll
    for (int f = 0; f < 16; f++) if (f < nf) {
#pragma unroll
      for (int r = 0; r < 4; r++) {
        float sv = sacc[f][r] * 0.125f;
        if (f * 16 + fr > qr0 + rq + r) sv = -3e38f;
        sacc[f][r] = sv;
        mr[r] = fmaxf(mr[r], sv);
      }
    }
#pragma unroll
    for (int msk = 1; msk < 16; msk <<= 1) {
#pragma unroll
      for (int r = 0; r < 4; r++) mr[r] = fmaxf(mr[r], __shfl_xor(mr[r], msk));
    }
    float ls[4] = {0.f, 0.f, 0.f, 0.f};
#pragma unroll
    for (int f = 0; f < 16; f++) if (f < nf) {
#pragma unroll
      for (int r = 0; r < 4; r++) {
        float p = __expf(sacc[f][r] - mr[r]);
        sacc[f][r] = p;
        ls[r] += p;
      }
    }
#pragma unroll
    for (int msk = 1; msk < 16; msk <<= 1) {
#pragma unroll
      for (int r = 0; r < 4; r++) ls[r] += __shfl_xor(ls[r], msk);
    }
#pragma unroll
    for (int f = 0; f < 16; f++) if (f < nf) {
#pragma unroll
      for (int r = 0; r < 4; r++)
        pw[(rq + r) * PPAD + f * 16 + fr] = f2bf(sacc[f][r]);
    }
    if (nf & 1) {
#pragma unroll
      for (int r = 0; r < 4; r++) pw[(rq + r) * PPAD + nf * 16 + fr] = 0;
    }
    f32x4 oc[4];
#pragma unroll
    for (int n = 0; n < 4; n++) oc[n] = f32x4{0.f, 0.f, 0.f, 0.f};
    const int kcs = (nf + 1) >> 1;
#pragma unroll
    for (int kc = 0; kc < 8; ++kc) if (kc < kcs) {
      short8 pa = *(const short8*)&pw[fr * PPAD + kc * 32 + fc];
#pragma unroll
      for (int n = 0; n < 4; n++) {
        short8 vf = *(const short8*)&vt_sm[(n * 16 + fr) * VPAD + kc * 32 + fc];
        oc[n] = __builtin_amdgcn_mfma_f32_16x16x32_bf16(pa, vf, oc[n], 0, 0, 0);
      }
    }
    float inv[4];
#pragma unroll
    for (int r = 0; r < 4; r++) inv[r] = 1.f / ls[r];
#pragma unroll
    for (int n = 0; n < 4; n++) {
#pragma unroll
      for (int r = 0; r < 4; r++)
        ob[obase + (size_t)(qr0 + rq + r) * 384 + n * 16 + fr] = f2bf(oc[n][r] * inv[r]);
    }
  }
}

// ---------------- orchestration ---------------------------------------------
extern "C" void kernel_launch(void* const* d_in, const int* in_sizes, int n_in,
                              void* d_out, int out_size, void* d_ws, size_t ws_size,
                              hipStream_t stream) {
  const float* x   = (const float*)d_in[0];
  const float* Wq  = (const float*)d_in[1];
  const float* Wk  = (const float*)d_in[2];
  const float* Wv  = (const float*)d_in[3];
  const float* Wo  = (const float*)d_in[4];
  const float* bo  = (const float*)d_in[5];
  const float* W1  = (const float*)d_in[6];
  const float* b1  = (const float*)d_in[7];
  const float* W2  = (const float*)d_in[8];
  const float* b2  = (const float*)d_in[9];
  const float* g1  = (const float*)d_in[10];
  const float* be1 = (const float*)d_in[11];
  const float* g2  = (const float*)d_in[12];
  const float* be2 = (const float*)d_in[13];
  float* out = (float*)d_out;
  char* ws = (char*)d_ws;

  // workspace layout (255.2 MB total; phases strictly ordered on the stream)
  bfu* wqkvT = (bfu*)(ws + 0);          // 1152x384 bf16 = 884736 B
  bfu* woT   = (bfu*)(ws + 884736);     // 294912
  bfu* w1T   = (bfu*)(ws + 1179648);    // 1179648
  bfu* w2T   = (bfu*)(ws + 2359296);    // 1179648
  char* H    = ws + 3538944;            // 50.3 MB: h2
  char* BIG  = H + 50331648;            // 201.3 MB: {h | attn} + qkv -> ab
  bfu* hb    = (bfu*)BIG;               // 50.3 MB (dead after QKV gemm)
  bfu* qkvb  = (bfu*)(BIG + 50331648);  // 151 MB (dead after attention)
  bfu* attnb = (bfu*)BIG;               // reuses hb region
  bfu* h2b   = (bfu*)H;
  bfu* ab    = (bfu*)BIG;               // 201.3 MB (clobbers attnb+qkvb, both dead)

  // 1) weights -> bf16 transposed (Wq/Wk/Wv packed into one [1152][384])
  transpose_w<<<576, 256, 0, stream>>>(Wq, wqkvT, 384, 384);
  transpose_w<<<576, 256, 0, stream>>>(Wk, wqkvT + 384 * 384, 384, 384);
  transpose_w<<<576, 256, 0, stream>>>(Wv, wqkvT + 2 * 384 * 384, 384, 384);
  transpose_w<<<576, 256, 0, stream>>>(Wo, woT, 384, 384);
  transpose_w<<<2304, 256, 0, stream>>>(W1, w1T, 384, 1536);
  transpose_w<<<2304, 256, 0, stream>>>(W2, w2T, 1536, 384);

  // 2) LN1
  ln_kernel<<<16384, 256, 0, stream>>>(x, g1, be1, hb);

  // 3) fused QKV GEMM (N=1152, bf16 out): 256 m-tiles x 9 n-tiles
  gemm_kernel<0, 0, 1><<<2304, 256, 0, stream>>>(hb, wqkvT, nullptr, qkvb, 1152, 384, 9);

  // 4) fused causal attention (reads packed qkv, stride 1152)
  attn_kernel<<<1536, 512, 0, stream>>>(qkvb, attnb);

  // 5) proj + bias + residual(x) + LN2 fused -> h2 (bf16)
  row_gemm<1><<<512, 512, 0, stream>>>(attnb, woT, bo, x, g2, be2, h2b, 384);

  // 6) FFN1 (+bias+ReLU, bf16 out): 256 m-tiles x 12 n-tiles
  gemm_kernel<1, 1, 1><<<3072, 256, 0, stream>>>(h2b, w1T, b1, ab, 1536, 384, 12);

  // 7) FFN2 + bias + residual(x) -> out (fp32)
  row_gemm<0><<<512, 512, 0, stream>>>(ab, w2T, b2, x, nullptr, nullptr, out, 1536);
}

// Round 6
// 509.555 us; speedup vs baseline: 1.0246x; 1.0199x over previous
//
#include <hip/hip_runtime.h>
#include <hip/hip_bf16.h>

typedef unsigned short bfu;
typedef __attribute__((ext_vector_type(8))) short short8;
typedef __attribute__((ext_vector_type(4))) float f32x4;

__device__ __forceinline__ bfu f2bf(float f) {
  return __builtin_bit_cast(bfu, __float2bfloat16(f));
}

__device__ __forceinline__ void gld16(const void* g, void* l) {
  __builtin_amdgcn_global_load_lds(
      (const __attribute__((address_space(1))) void*)g,
      (__attribute__((address_space(3))) void*)l, 16, 0, 0);
}

// ---- swizzle for [rows][64]-bf16 tiles (128B rows, 8 x 16B slots per row):
// phys_slot = slot ^ (row & 7). 64-lane frag read -> uniform 8 accesses/bank.
__device__ __forceinline__ int swz8(int row, int sl) {
  return (row << 7) + (((sl ^ (row & 7)) & 7) << 4);
}

// ---- swizzle for [rows][32]-bf16 tiles (64B rows) used by row_gemm --------
__device__ __forceinline__ int swz(int row, int slot) {
  const int unit = row >> 1;
  const int s8 = ((row & 1) << 2) | slot;
  return (unit << 7) + (((s8 ^ unit) & 7) << 4) + ((s8 >> 3) << 7);
}
__device__ __forceinline__ void unswz(int p, int& row, int& colel) {
  const int unit = p >> 7;
  const int s8 = ((p >> 4) & 7) ^ (unit & 7);
  row = (unit << 1) | (s8 >> 2);
  colel = (s8 & 3) << 3;
}

// ---------------- all weight transposes in ONE launch -----------------------
__global__ void transpose_all(const float* __restrict__ Wq, const float* __restrict__ Wk,
                              const float* __restrict__ Wv, const float* __restrict__ Wo,
                              const float* __restrict__ W1, const float* __restrict__ W2,
                              bfu* __restrict__ wqkvT, bfu* __restrict__ woT,
                              bfu* __restrict__ w1T, bfu* __restrict__ w2T) {
  int idx = blockIdx.x * 256 + threadIdx.x;
  if (idx < 4 * 147456) {
    int r = idx / 147456, i = idx - r * 147456;
    int k = i / 384, n = i - k * 384;
    const float* W = r == 0 ? Wq : r == 1 ? Wk : r == 2 ? Wv : Wo;
    bfu* dst = r < 3 ? wqkvT + r * 147456 : woT;
    dst[n * 384 + k] = f2bf(W[i]);
  } else if (idx < 4 * 147456 + 589824) {
    int i = idx - 4 * 147456;
    int k = i / 1536, n = i - k * 1536;
    w1T[n * 384 + k] = f2bf(W1[i]);
  } else if (idx < 4 * 147456 + 2 * 589824) {
    int i = idx - 4 * 147456 - 589824;
    int k = i / 384, n = i - k * 384;
    w2T[(size_t)n * 1536 + k] = f2bf(W2[i]);
  }
}

// ---------------- LayerNorm: one wave per row of 384 ------------------------
__launch_bounds__(256)
__global__ void ln_kernel(const float* __restrict__ in, const float* __restrict__ g,
                          const float* __restrict__ be, bfu* __restrict__ out) {
  const int wv = threadIdx.x >> 6, ln = threadIdx.x & 63;
  const size_t row = (size_t)blockIdx.x * 4 + wv;
  const float* p = in + row * 384;
  float v[6], s = 0.f, ss = 0.f;
#pragma unroll
  for (int i = 0; i < 6; i++) { v[i] = p[i * 64 + ln]; s += v[i]; ss += v[i] * v[i]; }
#pragma unroll
  for (int m = 1; m < 64; m <<= 1) { s += __shfl_xor(s, m); ss += __shfl_xor(ss, m); }
  const float mean = s * (1.f / 384.f);
  const float rs = rsqrtf(ss * (1.f / 384.f) - mean * mean + 1e-5f);
  bfu* q = out + row * 384;
#pragma unroll
  for (int i = 0; i < 6; i++) {
    const int c = i * 64 + ln;
    q[c] = f2bf((v[i] - mean) * rs * g[c] + be[c]);
  }
}

// ---------------- phase-split GEMM: C[M,N] = A[M,K] @ Bt[N,K]^T -------------
// BM=256, BN=128, BK=64, 512 threads (8 waves of 64x64). 3 LDS K-tile slots
// (144 KB), 2 phases per K-tile; each phase: 8 ds_read -> bar -> lgkm0 ->
// setprio(1) 16 MFMA setprio(0) -> bar. Stage for kt+2 issued at P0; each
// wave retires its OWN stage (counted vmcnt) before the barrier that
// publishes the slot (cross-wave visibility via barrier).
template <int BIAS, int RELU, int RES, int OUTBF>
__launch_bounds__(512)
__global__ void gemm8p(const bfu* __restrict__ A, const bfu* __restrict__ Bt,
                       const float* __restrict__ bias, const float* __restrict__ res,
                       void* __restrict__ Cout, int N, int K, int ntn) {
  __shared__ bfu sm[3][384 * 64];   // per slot: A[256][64] then B[128][64]
  const int tid = threadIdx.x;
  const int wv = tid >> 6, ln = tid & 63;
  const int cpx = gridDim.x >> 3;   // grid % 8 == 0 at all call sites
  const int wg = (blockIdx.x & 7) * cpx + (blockIdx.x >> 3);
  const int bm = wg / ntn, bn = wg - bm * ntn;
  const int m0 = bm << 8, n0 = bn << 7;
  const int wr = wv >> 1, wc = wv & 1;   // 4x2 waves; wave tile 64 rows x 64 cols
  const int fr = ln & 15, fslot = ln >> 4;

  f32x4 acc[4][4];
#pragma unroll
  for (int i = 0; i < 4; i++)
#pragma unroll
    for (int j = 0; j < 4; j++) acc[i][j] = f32x4{0.f, 0.f, 0.f, 0.f};

  const int lr = ln >> 3;             // staging: row-within-8-row chunk
  const int lslot = (ln & 7) ^ lr;    // logical k-slot (inverse swizzle)

  auto stage = [&](int s, int kt) {   // 6 gld16 per lane (4 A chunks + 2 B)
    char* smA = (char*)sm[s];
    char* smB = smA + 256 * 64 * 2;
    const int kcol = (kt << 6) + (lslot << 3);
#pragma unroll
    for (int i = 0; i < 4; ++i) {
      const int c = (wv << 2) + i;                     // A chunks 0..31
      gld16(A + (size_t)(m0 + (c << 3) + lr) * K + kcol, smA + (c << 10));
    }
#pragma unroll
    for (int i = 0; i < 2; ++i) {
      const int c = (wv << 1) + i;                     // B chunks 0..15
      gld16(Bt + (size_t)(n0 + (c << 3) + lr) * K + kcol, smB + (c << 10));
    }
  };

  const int nk = K >> 6;
  stage(0, 0);
  if (nk > 1) {
    stage(1, 1);
    asm volatile("s_waitcnt vmcnt(6)" ::: "memory");   // retire ST(0), leave ST(1)
  } else {
    asm volatile("s_waitcnt vmcnt(0)" ::: "memory");
  }
  __builtin_amdgcn_s_barrier();                         // publish slot 0

  for (int kt = 0; kt < nk; ++kt) {
    const int s = kt - (kt / 3) * 3;
    const char* smA = (const char*)sm[s];
    const char* smB = smA + 256 * 64 * 2;
    if (kt + 2 < nk) stage((kt + 2) - ((kt + 2) / 3) * 3, kt + 2);
    short8 af[4], bf[4];
    // ---- phase 0: k 0..31 of this K-tile
#pragma unroll
    for (int mi = 0; mi < 4; mi++)
      af[mi] = *(const short8*)(smA + swz8(wr * 64 + mi * 16 + fr, fslot));
#pragma unroll
    for (int ni = 0; ni < 4; ni++)
      bf[ni] = *(const short8*)(smB + swz8(wc * 64 + ni * 16 + fr, fslot));
    __builtin_amdgcn_s_barrier();
    asm volatile("s_waitcnt lgkmcnt(0)" ::: "memory");
    __builtin_amdgcn_sched_barrier(0);
    __builtin_amdgcn_s_setprio(1);
#pragma unroll
    for (int mi = 0; mi < 4; mi++)
#pragma unroll
      for (int ni = 0; ni < 4; ni++)
        acc[mi][ni] = __builtin_amdgcn_mfma_f32_16x16x32_bf16(af[mi], bf[ni], acc[mi][ni], 0, 0, 0);
    __builtin_amdgcn_s_setprio(0);
    __builtin_amdgcn_s_barrier();
    // ---- phase 1: k 32..63
#pragma unroll
    for (int mi = 0; mi < 4; mi++)
      af[mi] = *(const short8*)(smA + swz8(wr * 64 + mi * 16 + fr, 4 + fslot));
#pragma unroll
    for (int ni = 0; ni < 4; ni++)
      bf[ni] = *(const short8*)(smB + swz8(wc * 64 + ni * 16 + fr, 4 + fslot));
    __builtin_amdgcn_s_barrier();
    asm volatile("s_waitcnt lgkmcnt(0)" ::: "memory");
    __builtin_amdgcn_sched_barrier(0);
    __builtin_amdgcn_s_setprio(1);
#pragma unroll
    for (int mi = 0; mi < 4; mi++)
#pragma unroll
      for (int ni = 0; ni < 4; ni++)
        acc[mi][ni] = __builtin_amdgcn_mfma_f32_16x16x32_bf16(af[mi], bf[ni], acc[mi][ni], 0, 0, 0);
    __builtin_amdgcn_s_setprio(0);
    // retire ST(kt+1) (needed next iter), leave ST(kt+2) in flight
    if (kt + 2 < nk)      asm volatile("s_waitcnt vmcnt(6)" ::: "memory");
    else if (kt + 1 < nk) asm volatile("s_waitcnt vmcnt(0)" ::: "memory");
    __builtin_amdgcn_s_barrier();   // publish slot (kt+1)%3 for next iteration
  }

  const int rq = (ln >> 4) << 2;
#pragma unroll
  for (int mi = 0; mi < 4; mi++) {
#pragma unroll
    for (int ni = 0; ni < 4; ni++) {
      const int row = m0 + wr * 64 + mi * 16 + rq;
      const int col = n0 + wc * 64 + ni * 16 + fr;
      float bv = 0.f;
      if (BIAS) bv = bias[col];
#pragma unroll
      for (int r = 0; r < 4; r++) {
        float v = acc[mi][ni][r] + bv;
        if (RELU) v = fmaxf(v, 0.f);
        const size_t idx = (size_t)(row + r) * N + col;
        if (RES) v += res[idx];
        if (OUTBF) ((bfu*)Cout)[idx] = f2bf(v);
        else       ((float*)Cout)[idx] = v;
      }
    }
  }
}

// ---------------- full-row GEMM (proj + LN2 fusion): C[M,384] ---------------
// BM=128, BN=384, 8 waves (2x4, 64x96 each), BK=32, 4-buffer ring, counted
// vmcnt. Epilogue: +bias +residual + LayerNorm (bf16 out).
template <int LN>
__launch_bounds__(512)
__global__ void row_gemm(const bfu* __restrict__ A, const bfu* __restrict__ Bt,
                         const float* __restrict__ bias, const float* __restrict__ res,
                         const float* __restrict__ g, const float* __restrict__ be,
                         void* __restrict__ Cout, int K) {
  __shared__ bfu a_sm[4][128 * 32];
  __shared__ bfu b_sm[4][384 * 32];
  __shared__ float lnp[4][128][2];
  const int tid = threadIdx.x;
  const int wv = tid >> 6, ln = tid & 63;
  const int wr = wv >> 2, wc = wv & 3;
  const int fr = ln & 15, fslot = ln >> 4;
  const int m0 = blockIdx.x << 7;

  f32x4 acc[4][6];
#pragma unroll
  for (int i = 0; i < 4; i++)
#pragma unroll
    for (int j = 0; j < 6; j++) acc[i][j] = f32x4{0.f, 0.f, 0.f, 0.f};

  auto stage = [&](int buf, int kt) {
#pragma unroll
    for (int i = 0; i < 4; ++i) {
      const int c = wv * 4 + i;
      const int cc = (c < 8) ? c : (c - 8);
      const int p = cc * 1024 + (ln << 4);
      int r, colel;
      unswz(p, r, colel);
      const int col = kt * 32 + colel;
      if (c < 8)
        gld16(A + (size_t)(m0 + r) * K + col, (char*)a_sm[buf] + cc * 1024);
      else
        gld16(Bt + (size_t)r * K + col, (char*)b_sm[buf] + cc * 1024);
    }
  };

  const int nk = K >> 5;
#pragma unroll
  for (int i = 0; i < 3; ++i)
    if (i < nk) stage(i, i);

  for (int kt = 0; kt < nk; ++kt) {
    const int rem = nk - 1 - kt;
    if (rem >= 2)      asm volatile("s_waitcnt vmcnt(8)" ::: "memory");
    else if (rem == 1) asm volatile("s_waitcnt vmcnt(4)" ::: "memory");
    else               asm volatile("s_waitcnt vmcnt(0)" ::: "memory");
    __builtin_amdgcn_s_barrier();
    __builtin_amdgcn_sched_barrier(0);
    if (kt + 3 < nk) stage((kt + 3) & 3, kt + 3);
    const int cb = kt & 3;
    short8 af[4], bfr[6];
#pragma unroll
    for (int mi = 0; mi < 4; mi++)
      af[mi] = *(const short8*)((const char*)a_sm[cb] + swz(wr * 64 + mi * 16 + fr, fslot));
#pragma unroll
    for (int ni = 0; ni < 6; ni++)
      bfr[ni] = *(const short8*)((const char*)b_sm[cb] + swz(wc * 96 + ni * 16 + fr, fslot));
    __builtin_amdgcn_s_setprio(1);
#pragma unroll
    for (int mi = 0; mi < 4; mi++)
#pragma unroll
      for (int ni = 0; ni < 6; ni++)
        acc[mi][ni] = __builtin_amdgcn_mfma_f32_16x16x32_bf16(af[mi], bfr[ni], acc[mi][ni], 0, 0, 0);
    __builtin_amdgcn_s_setprio(0);
  }

  const int rq = (ln >> 4) << 2;
#pragma unroll
  for (int mi = 0; mi < 4; mi++) {
    const int row = wr * 64 + mi * 16 + rq;
#pragma unroll
    for (int ni = 0; ni < 6; ni++) {
      const int col = wc * 96 + ni * 16 + fr;
      const float bv = bias[col];
#pragma unroll
      for (int r = 0; r < 4; r++)
        acc[mi][ni][r] += bv + res[(size_t)(m0 + row + r) * 384 + col];
    }
  }

  if (LN) {
#pragma unroll
    for (int mi = 0; mi < 4; mi++) {
      float s[4] = {0.f, 0.f, 0.f, 0.f}, ss[4] = {0.f, 0.f, 0.f, 0.f};
#pragma unroll
      for (int ni = 0; ni < 6; ni++)
#pragma unroll
        for (int r = 0; r < 4; r++) {
          const float v = acc[mi][ni][r];
          s[r] += v; ss[r] += v * v;
        }
#pragma unroll
      for (int m = 1; m < 16; m <<= 1)
#pragma unroll
        for (int r = 0; r < 4; r++) {
          s[r] += __shfl_xor(s[r], m);
          ss[r] += __shfl_xor(ss[r], m);
        }
      if (fr == 0) {
#pragma unroll
        for (int r = 0; r < 4; r++) {
          lnp[wc][wr * 64 + mi * 16 + rq + r][0] = s[r];
          lnp[wc][wr * 64 + mi * 16 + rq + r][1] = ss[r];
        }
      }
    }
    __syncthreads();
#pragma unroll
    for (int mi = 0; mi < 4; mi++) {
#pragma unroll
      for (int r = 0; r < 4; r++) {
        const int row = wr * 64 + mi * 16 + rq + r;
        const float sm = lnp[0][row][0] + lnp[1][row][0] + lnp[2][row][0] + lnp[3][row][0];
        const float sq = lnp[0][row][1] + lnp[1][row][1] + lnp[2][row][1] + lnp[3][row][1];
        const float mean = sm * (1.f / 384.f);
        const float rs = rsqrtf(sq * (1.f / 384.f) - mean * mean + 1e-5f);
#pragma unroll
        for (int ni = 0; ni < 6; ni++) {
          const int col = wc * 96 + ni * 16 + fr;
          ((bfu*)Cout)[(size_t)(m0 + row) * 384 + col] =
              f2bf((acc[mi][ni][r] - mean) * rs * g[col] + be[col]);
        }
      }
    }
  } else {
#pragma unroll
    for (int mi = 0; mi < 4; mi++) {
      const int row = wr * 64 + mi * 16 + rq;
#pragma unroll
      for (int ni = 0; ni < 6; ni++) {
        const int col = wc * 96 + ni * 16 + fr;
#pragma unroll
        for (int r = 0; r < 4; r++)
          ((float*)Cout)[(size_t)(m0 + row + r) * 384 + col] = acc[mi][ni][r];
      }
    }
  }
}

// ---------------- fused causal attention: 1 block per (b,h), 8 waves --------
#define KPAD 72
#define VPAD 264
#define PPAD 264

__launch_bounds__(512)
__global__ void attn_kernel(const bfu* __restrict__ qkv, bfu* __restrict__ ob) {
  __shared__ bfu k_sm[256 * KPAD];
  __shared__ bfu vt_sm[64 * VPAD];
  __shared__ bfu p_sm[8 * 16 * PPAD];
  const int b = blockIdx.x / 6, h = blockIdx.x - b * 6;
  const int tid = threadIdx.x;
  const int wv = tid >> 6, ln = tid & 63;
  const int fr = ln & 15, fc = (ln >> 4) << 3;
  const size_t inbase = (size_t)b * 256 * 1152 + h * 64;
  const bfu* qb = qkv + inbase;
  const bfu* kb = qkv + inbase + 384;
  const bfu* vb = qkv + inbase + 768;
  const size_t obase = (size_t)b * 256 * 384 + h * 64;

  {
    const int row = tid >> 1;
    const int dh = (tid & 1) << 5;
    const bfu* kg = kb + (size_t)row * 1152 + dh;
    const bfu* vg = vb + (size_t)row * 1152 + dh;
#pragma unroll
    for (int i = 0; i < 4; i++) {
      short8 t8 = *(const short8*)(kg + i * 8);
      *(short8*)&k_sm[row * KPAD + dh + i * 8] = t8;
      short8 v8 = *(const short8*)(vg + i * 8);
#pragma unroll
      for (int j = 0; j < 8; j++)
        vt_sm[(dh + i * 8 + j) * VPAD + row] = (bfu)v8[j];
    }
  }
  __syncthreads();

  bfu* pw = &p_sm[wv * 16 * PPAD];
  const int rq = (ln >> 4) << 2;

#pragma unroll
  for (int si = 0; si < 2; ++si) {
    const int s = si ? (15 - wv) : wv;
    const int qr0 = s << 4;
    const int nf = s + 1;
    short8 aq[2];
#pragma unroll
    for (int dc = 0; dc < 2; dc++)
      aq[dc] = *(const short8*)(qb + (size_t)(qr0 + fr) * 1152 + dc * 32 + fc);

    f32x4 sacc[16];
#pragma unroll
    for (int f = 0; f < 16; f++) sacc[f] = f32x4{0.f, 0.f, 0.f, 0.f};
#pragma unroll
    for (int f = 0; f < 16; f++) if (f < nf) {
#pragma unroll
      for (int dc = 0; dc < 2; dc++) {
        short8 kf = *(const short8*)&k_sm[(f * 16 + fr) * KPAD + dc * 32 + fc];
        sacc[f] = __builtin_amdgcn_mfma_f32_16x16x32_bf16(aq[dc], kf, sacc[f], 0, 0, 0);
      }
    }
    float mr[4] = {-3e38f, -3e38f, -3e38f, -3e38f};
#pragma unroll
    for (int f = 0; f < 16; f++) if (f < nf) {
#pragma unroll
      for (int r = 0; r < 4; r++) {
        float sv = sacc[f][r] * 0.125f;
        if (f * 16 + fr > qr0 + rq + r) sv = -3e38f;
        sacc[f][r] = sv;
        mr[r] = fmaxf(mr[r], sv);
      }
    }
#pragma unroll
    for (int msk = 1; msk < 16; msk <<= 1) {
#pragma unroll
      for (int r = 0; r < 4; r++) mr[r] = fmaxf(mr[r], __shfl_xor(mr[r], msk));
    }
    float ls[4] = {0.f, 0.f, 0.f, 0.f};
#pragma unroll
    for (int f = 0; f < 16; f++) if (f < nf) {
#pragma unroll
      for (int r = 0; r < 4; r++) {
        float p = __expf(sacc[f][r] - mr[r]);
        sacc[f][r] = p;
        ls[r] += p;
      }
    }
#pragma unroll
    for (int msk = 1; msk < 16; msk <<= 1) {
#pragma unroll
      for (int r = 0; r < 4; r++) ls[r] += __shfl_xor(ls[r], msk);
    }
#pragma unroll
    for (int f = 0; f < 16; f++) if (f < nf) {
#pragma unroll
      for (int r = 0; r < 4; r++)
        pw[(rq + r) * PPAD + f * 16 + fr] = f2bf(sacc[f][r]);
    }
    if (nf & 1) {
#pragma unroll
      for (int r = 0; r < 4; r++) pw[(rq + r) * PPAD + nf * 16 + fr] = 0;
    }
    f32x4 oc[4];
#pragma unroll
    for (int n = 0; n < 4; n++) oc[n] = f32x4{0.f, 0.f, 0.f, 0.f};
    const int kcs = (nf + 1) >> 1;
#pragma unroll
    for (int kc = 0; kc < 8; ++kc) if (kc < kcs) {
      short8 pa = *(const short8*)&pw[fr * PPAD + kc * 32 + fc];
#pragma unroll
      for (int n = 0; n < 4; n++) {
        short8 vf = *(const short8*)&vt_sm[(n * 16 + fr) * VPAD + kc * 32 + fc];
        oc[n] = __builtin_amdgcn_mfma_f32_16x16x32_bf16(pa, vf, oc[n], 0, 0, 0);
      }
    }
    float inv[4];
#pragma unroll
    for (int r = 0; r < 4; r++) inv[r] = 1.f / ls[r];
#pragma unroll
    for (int n = 0; n < 4; n++) {
#pragma unroll
      for (int r = 0; r < 4; r++)
        ob[obase + (size_t)(qr0 + rq + r) * 384 + n * 16 + fr] = f2bf(oc[n][r] * inv[r]);
    }
  }
}

// ---------------- orchestration ---------------------------------------------
extern "C" void kernel_launch(void* const* d_in, const int* in_sizes, int n_in,
                              void* d_out, int out_size, void* d_ws, size_t ws_size,
                              hipStream_t stream) {
  const float* x   = (const float*)d_in[0];
  const float* Wq  = (const float*)d_in[1];
  const float* Wk  = (const float*)d_in[2];
  const float* Wv  = (const float*)d_in[3];
  const float* Wo  = (const float*)d_in[4];
  const float* bo  = (const float*)d_in[5];
  const float* W1  = (const float*)d_in[6];
  const float* b1  = (const float*)d_in[7];
  const float* W2  = (const float*)d_in[8];
  const float* b2  = (const float*)d_in[9];
  const float* g1  = (const float*)d_in[10];
  const float* be1 = (const float*)d_in[11];
  const float* g2  = (const float*)d_in[12];
  const float* be2 = (const float*)d_in[13];
  float* out = (float*)d_out;
  char* ws = (char*)d_ws;

  bfu* wqkvT = (bfu*)(ws + 0);          // 1152x384 bf16
  bfu* woT   = (bfu*)(ws + 884736);
  bfu* w1T   = (bfu*)(ws + 1179648);    // 1536x384
  bfu* w2T   = (bfu*)(ws + 2359296);    // 384x1536
  char* H    = ws + 3538944;            // 50.3 MB: h2
  char* BIG  = H + 50331648;            // 201.3 MB
  bfu* hb    = (bfu*)BIG;
  bfu* qkvb  = (bfu*)(BIG + 50331648);
  bfu* attnb = (bfu*)BIG;
  bfu* h2b   = (bfu*)H;
  bfu* ab    = (bfu*)BIG;

  // 1) all weight transposes (one launch)
  transpose_all<<<6912, 256, 0, stream>>>(Wq, Wk, Wv, Wo, W1, W2, wqkvT, woT, w1T, w2T);

  // 2) LN1
  ln_kernel<<<16384, 256, 0, stream>>>(x, g1, be1, hb);

  // 3) fused QKV GEMM (N=1152): 256 x 9 tiles
  gemm8p<0, 0, 0, 1><<<2304, 512, 0, stream>>>(hb, wqkvT, nullptr, nullptr, qkvb, 1152, 384, 9);

  // 4) fused causal attention
  attn_kernel<<<1536, 512, 0, stream>>>(qkvb, attnb);

  // 5) proj + bias + residual(x) + LN2 fused -> h2 (bf16)
  row_gemm<1><<<512, 512, 0, stream>>>(attnb, woT, bo, x, g2, be2, h2b, 384);

  // 6) FFN1 (+bias+ReLU): 256 x 12 tiles
  gemm8p<1, 1, 0, 1><<<3072, 512, 0, stream>>>(h2b, w1T, b1, nullptr, ab, 1536, 384, 12);

  // 7) FFN2 + bias + residual(x) -> out (fp32): 256 x 3 tiles
  gemm8p<1, 0, 1, 0><<<768, 512, 0, stream>>>(ab, w2T, b2, x, out, 384, 1536, 3);
}

// Round 7
// 493.478 us; speedup vs baseline: 1.0580x; 1.0326x over previous
//
#include <hip/hip_runtime.h>
#include <hip/hip_bf16.h>

typedef unsigned short bfu;
typedef __attribute__((ext_vector_type(8))) short short8;
typedef __attribute__((ext_vector_type(4))) float f32x4;

__device__ __forceinline__ bfu f2bf(float f) {
  return __builtin_bit_cast(bfu, __float2bfloat16(f));
}

__device__ __forceinline__ void gld16(const void* g, void* l) {
  __builtin_amdgcn_global_load_lds(
      (const __attribute__((address_space(1))) void*)g,
      (__attribute__((address_space(3))) void*)l, 16, 0, 0);
}

// ---- swizzle for [rows][64]-bf16 tiles (128B rows, 8 x 16B slots per row):
// phys_slot = slot ^ (row & 7).
__device__ __forceinline__ int swz8(int row, int sl) {
  return (row << 7) + (((sl ^ (row & 7)) & 7) << 4);
}

// ---- swizzle for [rows][32]-bf16 tiles (64B rows) used by row_gemm --------
__device__ __forceinline__ int swz(int row, int slot) {
  const int unit = row >> 1;
  const int s8 = ((row & 1) << 2) | slot;
  return (unit << 7) + (((s8 ^ unit) & 7) << 4) + ((s8 >> 3) << 7);
}
__device__ __forceinline__ void unswz(int p, int& row, int& colel) {
  const int unit = p >> 7;
  const int s8 = ((p >> 4) & 7) ^ (unit & 7);
  row = (unit << 1) | (s8 >> 2);
  colel = (s8 & 3) << 3;
}

// ---------------- all weight transposes in ONE launch -----------------------
__global__ void transpose_all(const float* __restrict__ Wq, const float* __restrict__ Wk,
                              const float* __restrict__ Wv, const float* __restrict__ Wo,
                              const float* __restrict__ W1, const float* __restrict__ W2,
                              bfu* __restrict__ wqkvT, bfu* __restrict__ woT,
                              bfu* __restrict__ w1T, bfu* __restrict__ w2T) {
  int idx = blockIdx.x * 256 + threadIdx.x;
  if (idx < 4 * 147456) {
    int r = idx / 147456, i = idx - r * 147456;
    int k = i / 384, n = i - k * 384;
    const float* W = r == 0 ? Wq : r == 1 ? Wk : r == 2 ? Wv : Wo;
    bfu* dst = r < 3 ? wqkvT + r * 147456 : woT;
    dst[n * 384 + k] = f2bf(W[i]);
  } else if (idx < 4 * 147456 + 589824) {
    int i = idx - 4 * 147456;
    int k = i / 1536, n = i - k * 1536;
    w1T[n * 384 + k] = f2bf(W1[i]);
  } else if (idx < 4 * 147456 + 2 * 589824) {
    int i = idx - 4 * 147456 - 589824;
    int k = i / 384, n = i - k * 384;
    w2T[(size_t)n * 1536 + k] = f2bf(W2[i]);
  }
}

// ---------------- LayerNorm: one wave per row of 384 ------------------------
__launch_bounds__(256)
__global__ void ln_kernel(const float* __restrict__ in, const float* __restrict__ g,
                          const float* __restrict__ be, bfu* __restrict__ out) {
  const int wv = threadIdx.x >> 6, ln = threadIdx.x & 63;
  const size_t row = (size_t)blockIdx.x * 4 + wv;
  const float* p = in + row * 384;
  float v[6], s = 0.f, ss = 0.f;
#pragma unroll
  for (int i = 0; i < 6; i++) { v[i] = p[i * 64 + ln]; s += v[i]; ss += v[i] * v[i]; }
#pragma unroll
  for (int m = 1; m < 64; m <<= 1) { s += __shfl_xor(s, m); ss += __shfl_xor(ss, m); }
  const float mean = s * (1.f / 384.f);
  const float rs = rsqrtf(ss * (1.f / 384.f) - mean * mean + 1e-5f);
  bfu* q = out + row * 384;
#pragma unroll
  for (int i = 0; i < 6; i++) {
    const int c = i * 64 + ln;
    q[c] = f2bf((v[i] - mean) * rs * g[c] + be[c]);
  }
}

// ---------------- fat-tile 4-phase GEMM: C[M,N] = A[M,K] @ Bt[N,K]^T --------
// BM = WM*32, BN = WN*64; 512 threads = 8 waves (2m x 4n), wave tile
// (WM*16) x (WN*16). BK=64, 2 LDS slots (double buffer). Per K-tile: 4 phases
// (mh, ks); B-frags read once per ks, reused across m-halves. Stage of K-tile
// kt+1 issued in phases 0 (A) and 1 (B); trailing vmcnt(0)+barrier publishes.
template <int WM, int WN, int BIAS, int RELU, int RES, int OUTBF>
__launch_bounds__(512)
__global__ void gemm_ph(const bfu* __restrict__ A, const bfu* __restrict__ Bt,
                        const float* __restrict__ bias, const float* __restrict__ res,
                        void* __restrict__ Cout, int N, int K, int ntn) {
  constexpr int BM = WM * 32;
  constexpr int BN = WN * 64;
  constexpr int ACH = BM / 64;     // A 1KB-chunks per wave
  constexpr int BCH = BN / 64;     // B 1KB-chunks per wave
  __shared__ bfu sm[2][(BM + BN) * 64];
  const int tid = threadIdx.x;
  const int wv = tid >> 6, ln = tid & 63;
  const int cpx = gridDim.x >> 3;            // grid % 8 == 0 at all call sites
  const int wg = (blockIdx.x & 7) * cpx + (blockIdx.x >> 3);
  const int bm = wg / ntn, bn = wg - bm * ntn;
  const int m0 = bm * BM, n0 = bn * BN;
  const int wr = wv >> 2, wc = wv & 3;       // 2m x 4n wave grid
  const int fr = ln & 15, fslot = ln >> 4;
  const int lr = ln >> 3, lsl = (ln & 7) ^ lr;   // staging row / logical slot

  f32x4 acc[WM][WN];
#pragma unroll
  for (int i = 0; i < WM; i++)
#pragma unroll
    for (int j = 0; j < WN; j++) acc[i][j] = f32x4{0.f, 0.f, 0.f, 0.f};

  auto stageA = [&](int s, int kt) {
    char* smA = (char*)sm[s];
    const int col = (kt << 6) + (lsl << 3);
#pragma unroll
    for (int i = 0; i < ACH; ++i) {
      const int c = wv * ACH + i;
      gld16(A + (size_t)(m0 + (c << 3) + lr) * K + col, smA + (c << 10));
    }
  };
  auto stageB = [&](int s, int kt) {
    char* smB = (char*)sm[s] + BM * 128;
    const int col = (kt << 6) + (lsl << 3);
#pragma unroll
    for (int i = 0; i < BCH; ++i) {
      const int c = wv * BCH + i;
      gld16(Bt + (size_t)(n0 + (c << 3) + lr) * K + col, smB + (c << 10));
    }
  };

  const int nk = K >> 6;
  stageA(0, 0);
  stageB(0, 0);
  asm volatile("s_waitcnt vmcnt(0)" ::: "memory");
  __builtin_amdgcn_s_barrier();

  for (int kt = 0; kt < nk; ++kt) {
    const int cur = kt & 1;
    const char* smA = (const char*)sm[cur];
    const char* smB = smA + BM * 128;
    short8 bf[2][WN];
#pragma unroll
    for (int ph = 0; ph < 4; ++ph) {
      const int mh = ph >> 1, ks = ph & 1;
      short8 af[WM / 2];
#pragma unroll
      for (int i = 0; i < WM / 2; ++i)
        af[i] = *(const short8*)(smA +
            swz8(wr * (WM * 16) + (mh * (WM / 2) + i) * 16 + fr, ks * 4 + fslot));
      if (mh == 0) {
#pragma unroll
        for (int ni = 0; ni < WN; ++ni)
          bf[ks][ni] = *(const short8*)(smB +
              swz8(wc * (WN * 16) + ni * 16 + fr, ks * 4 + fslot));
      }
      if (kt + 1 < nk) {
        if (ph == 0) stageA(cur ^ 1, kt + 1);
        if (ph == 1) stageB(cur ^ 1, kt + 1);
      }
      __builtin_amdgcn_s_barrier();
      asm volatile("s_waitcnt lgkmcnt(0)" ::: "memory");
      __builtin_amdgcn_sched_barrier(0);
      __builtin_amdgcn_s_setprio(1);
#pragma unroll
      for (int i = 0; i < WM / 2; ++i)
#pragma unroll
        for (int ni = 0; ni < WN; ++ni)
          acc[mh * (WM / 2) + i][ni] = __builtin_amdgcn_mfma_f32_16x16x32_bf16(
              af[i], bf[ks][ni], acc[mh * (WM / 2) + i][ni], 0, 0, 0);
      __builtin_amdgcn_s_setprio(0);
      __builtin_amdgcn_s_barrier();
    }
    if (kt + 1 < nk) {
      // stage loads for kt+1 were issued 2-3 phases ago; drain and publish
      asm volatile("s_waitcnt vmcnt(0)" ::: "memory");
      __builtin_amdgcn_s_barrier();
    }
  }

  const int rq = (ln >> 4) << 2;
#pragma unroll
  for (int mi = 0; mi < WM; mi++) {
#pragma unroll
    for (int ni = 0; ni < WN; ni++) {
      const int row = m0 + wr * (WM * 16) + mi * 16 + rq;
      const int col = n0 + wc * (WN * 16) + ni * 16 + fr;
      float bv = 0.f;
      if (BIAS) bv = bias[col];
#pragma unroll
      for (int r = 0; r < 4; r++) {
        float v = acc[mi][ni][r] + bv;
        if (RELU) v = fmaxf(v, 0.f);
        const size_t idx = (size_t)(row + r) * N + col;
        if (RES) v += res[idx];
        if (OUTBF) ((bfu*)Cout)[idx] = f2bf(v);
        else       ((float*)Cout)[idx] = v;
      }
    }
  }
}

// ---------------- full-row GEMM (proj + LN2 fusion): C[M,384] ---------------
// BM=128, BN=384, 8 waves (2x4, 64x96 each), BK=32, 4-buffer ring, counted
// vmcnt. Epilogue: +bias +residual + LayerNorm (bf16 out).
__launch_bounds__(512)
__global__ void row_gemm(const bfu* __restrict__ A, const bfu* __restrict__ Bt,
                         const float* __restrict__ bias, const float* __restrict__ res,
                         const float* __restrict__ g, const float* __restrict__ be,
                         void* __restrict__ Cout, int K) {
  __shared__ bfu a_sm[4][128 * 32];
  __shared__ bfu b_sm[4][384 * 32];
  __shared__ float lnp[4][128][2];
  const int tid = threadIdx.x;
  const int wv = tid >> 6, ln = tid & 63;
  const int wr = wv >> 2, wc = wv & 3;
  const int fr = ln & 15, fslot = ln >> 4;
  const int m0 = blockIdx.x << 7;

  f32x4 acc[4][6];
#pragma unroll
  for (int i = 0; i < 4; i++)
#pragma unroll
    for (int j = 0; j < 6; j++) acc[i][j] = f32x4{0.f, 0.f, 0.f, 0.f};

  auto stage = [&](int buf, int kt) {
#pragma unroll
    for (int i = 0; i < 4; ++i) {
      const int c = wv * 4 + i;
      const int cc = (c < 8) ? c : (c - 8);
      const int p = cc * 1024 + (ln << 4);
      int r, colel;
      unswz(p, r, colel);
      const int col = kt * 32 + colel;
      if (c < 8)
        gld16(A + (size_t)(m0 + r) * K + col, (char*)a_sm[buf] + cc * 1024);
      else
        gld16(Bt + (size_t)r * K + col, (char*)b_sm[buf] + cc * 1024);
    }
  };

  const int nk = K >> 5;
#pragma unroll
  for (int i = 0; i < 3; ++i)
    if (i < nk) stage(i, i);

  for (int kt = 0; kt < nk; ++kt) {
    const int rem = nk - 1 - kt;
    if (rem >= 2)      asm volatile("s_waitcnt vmcnt(8)" ::: "memory");
    else if (rem == 1) asm volatile("s_waitcnt vmcnt(4)" ::: "memory");
    else               asm volatile("s_waitcnt vmcnt(0)" ::: "memory");
    __builtin_amdgcn_s_barrier();
    __builtin_amdgcn_sched_barrier(0);
    if (kt + 3 < nk) stage((kt + 3) & 3, kt + 3);
    const int cb = kt & 3;
    short8 af[4], bfr[6];
#pragma unroll
    for (int mi = 0; mi < 4; mi++)
      af[mi] = *(const short8*)((const char*)a_sm[cb] + swz(wr * 64 + mi * 16 + fr, fslot));
#pragma unroll
    for (int ni = 0; ni < 6; ni++)
      bfr[ni] = *(const short8*)((const char*)b_sm[cb] + swz(wc * 96 + ni * 16 + fr, fslot));
    __builtin_amdgcn_s_setprio(1);
#pragma unroll
    for (int mi = 0; mi < 4; mi++)
#pragma unroll
      for (int ni = 0; ni < 6; ni++)
        acc[mi][ni] = __builtin_amdgcn_mfma_f32_16x16x32_bf16(af[mi], bfr[ni], acc[mi][ni], 0, 0, 0);
    __builtin_amdgcn_s_setprio(0);
  }

  const int rq = (ln >> 4) << 2;
#pragma unroll
  for (int mi = 0; mi < 4; mi++) {
    const int row = wr * 64 + mi * 16 + rq;
#pragma unroll
    for (int ni = 0; ni < 6; ni++) {
      const int col = wc * 96 + ni * 16 + fr;
      const float bv = bias[col];
#pragma unroll
      for (int r = 0; r < 4; r++)
        acc[mi][ni][r] += bv + res[(size_t)(m0 + row + r) * 384 + col];
    }
  }

#pragma unroll
  for (int mi = 0; mi < 4; mi++) {
    float s[4] = {0.f, 0.f, 0.f, 0.f}, ss[4] = {0.f, 0.f, 0.f, 0.f};
#pragma unroll
    for (int ni = 0; ni < 6; ni++)
#pragma unroll
      for (int r = 0; r < 4; r++) {
        const float v = acc[mi][ni][r];
        s[r] += v; ss[r] += v * v;
      }
#pragma unroll
    for (int m = 1; m < 16; m <<= 1)
#pragma unroll
      for (int r = 0; r < 4; r++) {
        s[r] += __shfl_xor(s[r], m);
        ss[r] += __shfl_xor(ss[r], m);
      }
    if (fr == 0) {
#pragma unroll
      for (int r = 0; r < 4; r++) {
        lnp[wc][wr * 64 + mi * 16 + rq + r][0] = s[r];
        lnp[wc][wr * 64 + mi * 16 + rq + r][1] = ss[r];
      }
    }
  }
  __syncthreads();
#pragma unroll
  for (int mi = 0; mi < 4; mi++) {
#pragma unroll
    for (int r = 0; r < 4; r++) {
      const int row = wr * 64 + mi * 16 + rq + r;
      const float sm = lnp[0][row][0] + lnp[1][row][0] + lnp[2][row][0] + lnp[3][row][0];
      const float sq = lnp[0][row][1] + lnp[1][row][1] + lnp[2][row][1] + lnp[3][row][1];
      const float mean = sm * (1.f / 384.f);
      const float rs = rsqrtf(sq * (1.f / 384.f) - mean * mean + 1e-5f);
#pragma unroll
      for (int ni = 0; ni < 6; ni++) {
        const int col = wc * 96 + ni * 16 + fr;
        ((bfu*)Cout)[(size_t)(m0 + row) * 384 + col] =
            f2bf((acc[mi][ni][r] - mean) * rs * g[col] + be[col]);
      }
    }
  }
}

// ---------------- fused causal attention: 1 block per (b,h), 8 waves --------
#define KPAD 72
#define VPAD 264
#define PPAD 264

__launch_bounds__(512)
__global__ void attn_kernel(const bfu* __restrict__ qkv, bfu* __restrict__ ob) {
  __shared__ bfu k_sm[256 * KPAD];
  __shared__ bfu vt_sm[64 * VPAD];
  __shared__ bfu p_sm[8 * 16 * PPAD];
  const int b = blockIdx.x / 6, h = blockIdx.x - b * 6;
  const int tid = threadIdx.x;
  const int wv = tid >> 6, ln = tid & 63;
  const int fr = ln & 15, fc = (ln >> 4) << 3;
  const size_t inbase = (size_t)b * 256 * 1152 + h * 64;
  const bfu* qb = qkv + inbase;
  const bfu* kb = qkv + inbase + 384;
  const bfu* vb = qkv + inbase + 768;
  const size_t obase = (size_t)b * 256 * 384 + h * 64;

  {
    const int row = tid >> 1;
    const int dh = (tid & 1) << 5;
    const bfu* kg = kb + (size_t)row * 1152 + dh;
    const bfu* vg = vb + (size_t)row * 1152 + dh;
#pragma unroll
    for (int i = 0; i < 4; i++) {
      short8 t8 = *(const short8*)(kg + i * 8);
      *(short8*)&k_sm[row * KPAD + dh + i * 8] = t8;
      short8 v8 = *(const short8*)(vg + i * 8);
#pragma unroll
      for (int j = 0; j < 8; j++)
        vt_sm[(dh + i * 8 + j) * VPAD + row] = (bfu)v8[j];
    }
  }
  __syncthreads();

  bfu* pw = &p_sm[wv * 16 * PPAD];
  const int rq = (ln >> 4) << 2;

#pragma unroll
  for (int si = 0; si < 2; ++si) {
    const int s = si ? (15 - wv) : wv;
    const int qr0 = s << 4;
    const int nf = s + 1;
    short8 aq[2];
#pragma unroll
    for (int dc = 0; dc < 2; dc++)
      aq[dc] = *(const short8*)(qb + (size_t)(qr0 + fr) * 1152 + dc * 32 + fc);

    f32x4 sacc[16];
#pragma unroll
    for (int f = 0; f < 16; f++) sacc[f] = f32x4{0.f, 0.f, 0.f, 0.f};
#pragma unroll
    for (int f = 0; f < 16; f++) if (f < nf) {
#pragma unroll
      for (int dc = 0; dc < 2; dc++) {
        short8 kf = *(const short8*)&k_sm[(f * 16 + fr) * KPAD + dc * 32 + fc];
        sacc[f] = __builtin_amdgcn_mfma_f32_16x16x32_bf16(aq[dc], kf, sacc[f], 0, 0, 0);
      }
    }
    float mr[4] = {-3e38f, -3e38f, -3e38f, -3e38f};
#pragma unroll
    for (int f = 0; f < 16; f++) if (f < nf) {
#pragma unroll
      for (int r = 0; r < 4; r++) {
        float sv = sacc[f][r] * 0.125f;
        if (f * 16 + fr > qr0 + rq + r) sv = -3e38f;
        sacc[f][r] = sv;
        mr[r] = fmaxf(mr[r], sv);
      }
    }
#pragma unroll
    for (int msk = 1; msk < 16; msk <<= 1) {
#pragma unroll
      for (int r = 0; r < 4; r++) mr[r] = fmaxf(mr[r], __shfl_xor(mr[r], msk));
    }
    float ls[4] = {0.f, 0.f, 0.f, 0.f};
#pragma unroll
    for (int f = 0; f < 16; f++) if (f < nf) {
#pragma unroll
      for (int r = 0; r < 4; r++) {
        float p = __expf(sacc[f][r] - mr[r]);
        sacc[f][r] = p;
        ls[r] += p;
      }
    }
#pragma unroll
    for (int msk = 1; msk < 16; msk <<= 1) {
#pragma unroll
      for (int r = 0; r < 4; r++) ls[r] += __shfl_xor(ls[r], msk);
    }
#pragma unroll
    for (int f = 0; f < 16; f++) if (f < nf) {
#pragma unroll
      for (int r = 0; r < 4; r++)
        pw[(rq + r) * PPAD + f * 16 + fr] = f2bf(sacc[f][r]);
    }
    if (nf & 1) {
#pragma unroll
      for (int r = 0; r < 4; r++) pw[(rq + r) * PPAD + nf * 16 + fr] = 0;
    }
    f32x4 oc[4];
#pragma unroll
    for (int n = 0; n < 4; n++) oc[n] = f32x4{0.f, 0.f, 0.f, 0.f};
    const int kcs = (nf + 1) >> 1;
#pragma unroll
    for (int kc = 0; kc < 8; ++kc) if (kc < kcs) {
      short8 pa = *(const short8*)&pw[fr * PPAD + kc * 32 + fc];
#pragma unroll
      for (int n = 0; n < 4; n++) {
        short8 vf = *(const short8*)&vt_sm[(n * 16 + fr) * VPAD + kc * 32 + fc];
        oc[n] = __builtin_amdgcn_mfma_f32_16x16x32_bf16(pa, vf, oc[n], 0, 0, 0);
      }
    }
    float inv[4];
#pragma unroll
    for (int r = 0; r < 4; r++) inv[r] = 1.f / ls[r];
#pragma unroll
    for (int n = 0; n < 4; n++) {
#pragma unroll
      for (int r = 0; r < 4; r++)
        ob[obase + (size_t)(qr0 + rq + r) * 384 + n * 16 + fr] = f2bf(oc[n][r] * inv[r]);
    }
  }
}

// ---------------- orchestration ---------------------------------------------
extern "C" void kernel_launch(void* const* d_in, const int* in_sizes, int n_in,
                              void* d_out, int out_size, void* d_ws, size_t ws_size,
                              hipStream_t stream) {
  const float* x   = (const float*)d_in[0];
  const float* Wq  = (const float*)d_in[1];
  const float* Wk  = (const float*)d_in[2];
  const float* Wv  = (const float*)d_in[3];
  const float* Wo  = (const float*)d_in[4];
  const float* bo  = (const float*)d_in[5];
  const float* W1  = (const float*)d_in[6];
  const float* b1  = (const float*)d_in[7];
  const float* W2  = (const float*)d_in[8];
  const float* b2  = (const float*)d_in[9];
  const float* g1  = (const float*)d_in[10];
  const float* be1 = (const float*)d_in[11];
  const float* g2  = (const float*)d_in[12];
  const float* be2 = (const float*)d_in[13];
  float* out = (float*)d_out;
  char* ws = (char*)d_ws;

  bfu* wqkvT = (bfu*)(ws + 0);          // 1152x384 bf16
  bfu* woT   = (bfu*)(ws + 884736);
  bfu* w1T   = (bfu*)(ws + 1179648);    // 1536x384
  bfu* w2T   = (bfu*)(ws + 2359296);    // 384x1536
  char* H    = ws + 3538944;            // 50.3 MB: h2
  char* BIG  = H + 50331648;            // 201.3 MB
  bfu* hb    = (bfu*)BIG;
  bfu* qkvb  = (bfu*)(BIG + 50331648);
  bfu* attnb = (bfu*)BIG;
  bfu* h2b   = (bfu*)H;
  bfu* ab    = (bfu*)BIG;

  // 1) all weight transposes (one launch)
  transpose_all<<<6912, 256, 0, stream>>>(Wq, Wk, Wv, Wo, W1, W2, wqkvT, woT, w1T, w2T);

  // 2) LN1
  ln_kernel<<<16384, 256, 0, stream>>>(x, g1, be1, hb);

  // 3) fused QKV GEMM (N=1152): 256 m-tiles x 6 n-tiles of 256x192
  gemm_ph<8, 3, 0, 0, 0, 1><<<1536, 512, 0, stream>>>(hb, wqkvT, nullptr, nullptr, qkvb, 1152, 384, 6);

  // 4) fused causal attention
  attn_kernel<<<1536, 512, 0, stream>>>(qkvb, attnb);

  // 5) proj + bias + residual(x) + LN2 fused -> h2 (bf16)
  row_gemm<<<512, 512, 0, stream>>>(attnb, woT, bo, x, g2, be2, h2b, 384);

  // 6) FFN1 (+bias+ReLU): 256 m-tiles x 6 n-tiles of 256x256
  gemm_ph<8, 4, 1, 1, 0, 1><<<1536, 512, 0, stream>>>(h2b, w1T, b1, nullptr, ab, 1536, 384, 6);

  // 7) FFN2 + bias + residual(x) -> out (fp32): 512 m-tiles x 1 n-tile of 128x384
  gemm_ph<4, 6, 1, 0, 1, 0><<<512, 512, 0, stream>>>(ab, w2T, b2, x, out, 384, 1536, 1);
}